// Round 1
// baseline (362.782 us; speedup 1.0000x reference)
//
#include <hip/hip_runtime.h>
#include <hip/hip_bf16.h>
#include <stdint.h>

#define NN 32
#define CI 256
#define CO 256
#define HH 56
#define WW 56
#define TPH 58
#define TPW 72
#define CNT (NN*HH*WW)   // 100352 elements per channel

typedef __bf16 bf16x8 __attribute__((ext_vector_type(8)));
typedef float  f32x4  __attribute__((ext_vector_type(4)));

// ---- async global->LDS 16B copy (wave-uniform LDS base + lane*16) ----
__device__ __forceinline__ void gld16(const void* g, void* l) {
    __builtin_amdgcn_global_load_lds(
        (const __attribute__((address_space(1))) void*)(uintptr_t)g,
        (__attribute__((address_space(3))) void*)(uint32_t)(uintptr_t)l,
        16, 0, 0);
}

__device__ __forceinline__ unsigned short f2bf(float f) {
    uint32_t u = __float_as_uint(f);
    uint32_t r = (u + 0x7FFFu + ((u >> 16) & 1u)) >> 16;
    return (unsigned short)r;
}

// ================= 1. per-channel stats (fp64 accumulate) =================
// stats[2c] = scale = gamma*invstd ; stats[2c+1] = shift = beta - mean*scale
__global__ void stats_kernel(const float* __restrict__ x,
                             const float* __restrict__ gamma,
                             const float* __restrict__ beta,
                             double* __restrict__ stats) {
    const int c = blockIdx.x;
    double s = 0.0, ss = 0.0;
    for (int idx = threadIdx.x; idx < NN * 784; idx += 256) {
        int n = idx / 784, q = idx % 784;
        const float4 v = *(const float4*)(x + ((size_t)n * CI + c) * 3136 + q * 4);
        double a = v.x, b = v.y, cc = v.z, d = v.w;
        s  += (a + b) + (cc + d);
        ss += (a * a + b * b) + (cc * cc + d * d);
    }
    for (int off = 32; off > 0; off >>= 1) {
        s  += __shfl_down(s, off, 64);
        ss += __shfl_down(ss, off, 64);
    }
    __shared__ double red[8];
    int wid = threadIdx.x >> 6, lane = threadIdx.x & 63;
    if (lane == 0) { red[wid] = s; red[4 + wid] = ss; }
    __syncthreads();
    if (threadIdx.x == 0) {
        double S  = (red[0] + red[1]) + (red[2] + red[3]);
        double SS = (red[4] + red[5]) + (red[6] + red[7]);
        double mean = S / (double)CNT;
        double var  = SS / (double)CNT - mean * mean;
        double invstd = 1.0 / sqrt(var + 1e-4);
        double scale = (double)gamma[c] * invstd;
        double shift = (double)beta[c] - mean * scale;
        stats[2 * c]     = scale;
        stats[2 * c + 1] = shift;
    }
}

// ================= 2. weight transform: OIHW fp32 -> [tap][chunk][co][ci32] bf16 ===
__global__ void wtrans_kernel(const float* __restrict__ w, unsigned short* __restrict__ wT) {
    int o = blockIdx.x * 256 + threadIdx.x;
    if (o < 9 * 8 * 256 * 32) {
        int ci_sub = o & 31;
        int co     = (o >> 5) & 255;
        int chunk  = (o >> 13) & 7;
        int tap    = o >> 16;            // kh*3+kw
        int ci     = chunk * 32 + ci_sub;
        wT[o] = f2bf(w[((size_t)co * 256 + ci) * 9 + tap]);
    }
}

// ================= 3. ternarize + NCHW->padded-NHWC bf16 ===================
// tp layout: [n][58][72][256] bf16, zero-initialized; interior rows 1..56, cols 1..56
__global__ void ternarize_kernel(const float* __restrict__ x,
                                 const double* __restrict__ stats,
                                 unsigned short* __restrict__ tp) {
    const int h = blockIdx.x, n = blockIdx.y;
    __shared__ unsigned short lds[CI][60];   // [ci][w], pad to 60
    const size_t xbase = ((size_t)n * CI) * 3136 + (size_t)h * 56;
    for (int idx = threadIdx.x; idx < CI * 14; idx += 256) {
        int ci = idx / 14, wq = idx % 14;
        const float4 v = *(const float4*)(x + xbase + (size_t)ci * 3136 + wq * 4);
        double sc = stats[2 * ci], sh = stats[2 * ci + 1];
        ushort4 t;
        t.x = (fma(sc, (double)v.x, sh) > 0.0) ? 0x3F80u : 0xBF80u;
        t.y = (fma(sc, (double)v.y, sh) > 0.0) ? 0x3F80u : 0xBF80u;
        t.z = (fma(sc, (double)v.z, sh) > 0.0) ? 0x3F80u : 0xBF80u;
        t.w = (fma(sc, (double)v.w, sh) > 0.0) ? 0x3F80u : 0xBF80u;
        *(ushort4*)&lds[ci][wq * 4] = t;
    }
    __syncthreads();
    unsigned short* outp = tp + (((size_t)n * TPH + h + 1) * TPW + 1) * CI;
    for (int idx = threadIdx.x; idx < 56 * 64; idx += 256) {
        int w = idx >> 6, cig = (idx & 63) << 2;
        ushort4 t;
        t.x = lds[cig][w]; t.y = lds[cig + 1][w];
        t.z = lds[cig + 2][w]; t.w = lds[cig + 3][w];
        *(ushort4*)&outp[(size_t)w * CI + cig] = t;
    }
}

// ================= 4. implicit-GEMM conv via MFMA bf16 =====================
// grid (co_t 2, h_t 28, n 32); block 256 = 4 waves; tile 128co x (2 rows x 64w)
__launch_bounds__(256, 2)
__global__ void conv_kernel(const unsigned short* __restrict__ wT,
                            const unsigned short* __restrict__ tp,
                            const float* __restrict__ bias,
                            float* __restrict__ out) {
    const int co_t = blockIdx.x;
    const int h0   = blockIdx.y * 2;
    const int n    = blockIdx.z;
    const int tid  = threadIdx.x;
    const int lane = tid & 63, wid = tid >> 6;
    const int l15 = lane & 15, q = lane >> 4;
    const int m_off = (wid & 1) * 64;     // co offset within 128
    const int rowsel = wid >> 1;          // which of the 2 output rows

    __shared__ unsigned short Blds[4 * TPW * 32];   // [row][wp][ci32]  18.4 KB
    __shared__ unsigned short Alds[3 * 128 * 32];   // [kw][co][ci32]   24.6 KB

    f32x4 acc[4][4];
#pragma unroll
    for (int i = 0; i < 4; ++i)
#pragma unroll
        for (int j = 0; j < 4; ++j) acc[i][j] = (f32x4){0.f, 0.f, 0.f, 0.f};

    for (int chunk = 0; chunk < 8; ++chunk) {
        const int ci0 = chunk * 32;
        __syncthreads();
        // ---- stage B: 4 rows x 72 wp x 32 ci = 1152 x 16B pieces ----
        {
            const unsigned short* gbase =
                tp + ((size_t)n * TPH + h0) * TPW * CI + ci0;
#pragma unroll
            for (int j = 0; j < 5; ++j) {
                int p = tid + j * 256;
                if (j < 4 || tid < 128) {
                    int row = p / 288, rem = p % 288;   // 288 = 72*4 pieces/row
                    int w = rem >> 2, c8 = rem & 3;
                    const unsigned short* g = gbase + ((size_t)row * TPW + w) * CI + c8 * 8;
                    gld16(g, ((char*)Blds) + p * 16);
                }
            }
        }
#pragma unroll
        for (int kh = 0; kh < 3; ++kh) {
            if (kh > 0) __syncthreads();
            // ---- stage A: 3 kw x 128co x 32ci (linear copies) ----
#pragma unroll
            for (int kw = 0; kw < 3; ++kw) {
                const unsigned short* gbase =
                    wT + (size_t)((((kh * 3 + kw) * 8 + chunk) * 256) + co_t * 128) * 32;
#pragma unroll
                for (int j = 0; j < 2; ++j) {
                    int p = tid + j * 256;
                    gld16(((const char*)gbase) + p * 16,
                          ((char*)Alds) + kw * 8192 + p * 16);
                }
            }
            __syncthreads();
            const int ldsrow = rowsel + kh;
#pragma unroll
            for (int kw = 0; kw < 3; ++kw) {
                bf16x8 b[4], a[4];
#pragma unroll
                for (int j = 0; j < 4; ++j) {
                    int wp = j * 16 + l15 + kw;
                    b[j] = *(const bf16x8*)&Blds[(ldsrow * TPW + wp) * 32 + q * 8];
                }
#pragma unroll
                for (int i = 0; i < 4; ++i) {
                    int co = m_off + i * 16 + l15;
                    a[i] = *(const bf16x8*)&Alds[(kw * 128 + co) * 32 + q * 8];
                }
#pragma unroll
                for (int i = 0; i < 4; ++i)
#pragma unroll
                    for (int j = 0; j < 4; ++j)
                        acc[i][j] = __builtin_amdgcn_mfma_f32_16x16x32_bf16(
                            a[i], b[j], acc[i][j], 0, 0, 0);
            }
        }
    }

    // ---- epilogue: bias + relu, store fp32 NCHW ----
    const int h_out = h0 + rowsel;
#pragma unroll
    for (int i = 0; i < 4; ++i) {
        int co = co_t * 128 + m_off + i * 16 + q * 4;
        const float4 bv = *(const float4*)&bias[co];
        float bb[4] = {bv.x, bv.y, bv.z, bv.w};
#pragma unroll
        for (int j = 0; j < 4; ++j) {
            int w = j * 16 + l15;
            if (w < 56) {
                size_t ob = (((size_t)n * CO + co) * HH + h_out) * WW + w;
#pragma unroll
                for (int r = 0; r < 4; ++r) {
                    float v = acc[i][j][r] + bb[r];
                    out[ob + (size_t)r * (HH * WW)] = v > 0.f ? v : 0.f;
                }
            }
        }
    }
}

// ================= launch =================
extern "C" void kernel_launch(void* const* d_in, const int* in_sizes, int n_in,
                              void* d_out, int out_size, void* d_ws, size_t ws_size,
                              hipStream_t stream) {
    const float* x      = (const float*)d_in[0];
    const float* gamma  = (const float*)d_in[1];
    const float* beta   = (const float*)d_in[2];
    const float* weight = (const float*)d_in[3];
    const float* bias   = (const float*)d_in[4];
    float* out = (float*)d_out;

    // workspace layout
    double* stats        = (double*)d_ws;                              // 4096 B
    unsigned short* wT   = (unsigned short*)((char*)d_ws + 4096);      // 1,179,648 B
    unsigned short* tp   = (unsigned short*)((char*)d_ws + 4096 + 1179648);
    const size_t tp_bytes = (size_t)NN * TPH * TPW * CI * 2;           // 68,419,584 B

    hipMemsetAsync(tp, 0, tp_bytes, stream);
    stats_kernel<<<256, 256, 0, stream>>>(x, gamma, beta, stats);
    wtrans_kernel<<<2304, 256, 0, stream>>>(weight, wT);
    ternarize_kernel<<<dim3(HH, NN), 256, 0, stream>>>(x, stats, tp);
    conv_kernel<<<dim3(2, 28, NN), 256, 0, stream>>>(wT, tp, bias, out);
}

// Round 2
// 327.133 us; speedup vs baseline: 1.1090x; 1.1090x over previous
//
#include <hip/hip_runtime.h>
#include <stdint.h>

#define NN 32
#define CI 256
#define CO 256
#define HH 56
#define WW 56
#define TPH 58
#define TPW 72
#define CNT (NN*HH*WW)

typedef int i32x4 __attribute__((ext_vector_type(4)));

// async global->LDS 16B (wave-uniform LDS base + lane*16)
__device__ __forceinline__ void gld16(const void* g, void* l) {
    __builtin_amdgcn_global_load_lds(
        (const __attribute__((address_space(1))) void*)(uintptr_t)g,
        (__attribute__((address_space(3))) void*)(uint32_t)(uintptr_t)l,
        16, 0, 0);
}

// ================= 1a. per-channel stats, 8-way split over n ==============
__global__ void stats_part(const float* __restrict__ x, double* __restrict__ part) {
    const int c = blockIdx.x, sp = blockIdx.y;           // sp: 4 images each
    double s = 0.0, ss = 0.0;
    const size_t base = ((size_t)(sp * 4) * CI + c) * 3136;
    for (int idx = threadIdx.x; idx < 4 * 784; idx += 256) {
        int nl = idx / 784, q = idx % 784;
        const float4 v = *(const float4*)(x + base + (size_t)nl * CI * 3136 + q * 4);
        double a = v.x, b = v.y, cc = v.z, d = v.w;
        s  += (a + b) + (cc + d);
        ss += (a * a + b * b) + (cc * cc + d * d);
    }
    for (int off = 32; off > 0; off >>= 1) {
        s  += __shfl_down(s, off, 64);
        ss += __shfl_down(ss, off, 64);
    }
    __shared__ double red[8];
    int wid = threadIdx.x >> 6, lane = threadIdx.x & 63;
    if (lane == 0) { red[wid] = s; red[4 + wid] = ss; }
    __syncthreads();
    if (threadIdx.x == 0) {
        part[(sp * 256 + c) * 2]     = (red[0] + red[1]) + (red[2] + red[3]);
        part[(sp * 256 + c) * 2 + 1] = (red[4] + red[5]) + (red[6] + red[7]);
    }
}

// ================= 1b. finalize: scale/shift per channel (fp64) ===========
__global__ void stats_final(const double* __restrict__ part,
                            const float* __restrict__ gamma,
                            const float* __restrict__ beta,
                            double* __restrict__ stats) {
    const int c = threadIdx.x;
    double S = 0.0, SS = 0.0;
    for (int sp = 0; sp < 8; ++sp) {
        S  += part[(sp * 256 + c) * 2];
        SS += part[(sp * 256 + c) * 2 + 1];
    }
    double mean = S / (double)CNT;
    double var  = SS / (double)CNT - mean * mean;
    double invstd = 1.0 / sqrt(var + 1e-4);
    double scale = (double)gamma[c] * invstd;
    double shift = (double)beta[c] - mean * scale;
    stats[2 * c]     = scale;
    stats[2 * c + 1] = shift;
}

// ================= 2. weight quant: per-co int8, layout [tap][chunk][co][ci64]
__global__ void wtrans_kernel(const float* __restrict__ w,
                              int8_t* __restrict__ wT,
                              float* __restrict__ qscale) {
    const int co = blockIdx.x;
    const float* wp = w + (size_t)co * 2304;
    float v[9], m = 0.f;
#pragma unroll
    for (int it = 0; it < 9; ++it) {
        v[it] = wp[threadIdx.x + it * 256];
        m = fmaxf(m, fabsf(v[it]));
    }
    for (int off = 32; off > 0; off >>= 1) m = fmaxf(m, __shfl_down(m, off, 64));
    __shared__ float red[4];
    __shared__ float qsh;
    int wid = threadIdx.x >> 6, lane = threadIdx.x & 63;
    if (lane == 0) red[wid] = m;
    __syncthreads();
    if (threadIdx.x == 0) {
        float mx = fmaxf(fmaxf(red[0], red[1]), fmaxf(red[2], red[3]));
        float q = (mx > 0.f) ? mx / 127.f : 1.f;
        qsh = q;
        qscale[co] = q;
    }
    __syncthreads();
    const float q = qsh;
#pragma unroll
    for (int it = 0; it < 9; ++it) {
        int idx = threadIdx.x + it * 256;
        int ci = idx / 9, tap = idx % 9;
        int chunk = ci >> 6, cis = ci & 63;
        int iq = __float2int_rn(v[it] / q);
        iq = iq > 127 ? 127 : (iq < -127 ? -127 : iq);
        wT[((size_t)(tap * 4 + chunk) * 256 + co) * 64 + cis] = (int8_t)iq;
    }
}

// ================= 3a. zero halo rows 0 and 57 ============================
__global__ void halo_kernel(int8_t* __restrict__ tp) {
    const int b = blockIdx.x, n = b >> 1, r = (b & 1) * 57;
    i32x4* dst = (i32x4*)(tp + ((size_t)n * TPH + r) * TPW * CI);
    const i32x4 z = {0, 0, 0, 0};
    for (int p = threadIdx.x; p < TPW * CI / 16; p += 256) dst[p] = z;
}

// ================= 3b. ternarize + NCHW -> padded-NHWC int8 ===============
__global__ void ternarize_kernel(const float* __restrict__ x,
                                 const double* __restrict__ stats,
                                 int8_t* __restrict__ tp) {
    const int h = blockIdx.x, n = blockIdx.y;
    __shared__ int8_t L[56 * 260];                 // [w][ci], padded stride 260
    const size_t xb = ((size_t)n * CI) * 3136 + (size_t)h * 56;
    for (int idx = threadIdx.x; idx < CI * 56; idx += 256) {
        int ci = idx / 56, w = idx - ci * 56;
        float val = x[xb + (size_t)ci * 3136 + w];
        double sc = stats[2 * ci], sh = stats[2 * ci + 1];
        L[w * 260 + ci] = (fma(sc, (double)val, sh) > 0.0) ? (int8_t)1 : (int8_t)-1;
    }
    __syncthreads();
    i32x4* rowp = (i32x4*)(tp + ((size_t)n * TPH + h + 1) * TPW * CI);
    for (int p = threadIdx.x; p < TPW * 16; p += 256) {
        int wo = p >> 4, c16 = p & 15;
        i32x4 v = {0, 0, 0, 0};
        if (wo >= 1 && wo <= 56) {
            const int* lp = (const int*)&L[(wo - 1) * 260 + c16 * 16];
            v.x = lp[0]; v.y = lp[1]; v.z = lp[2]; v.w = lp[3];
        }
        rowp[p] = v;
    }
}

// ================= 4. implicit-GEMM conv, int8 MFMA, dbuf LDS =============
// grid (2, 28, 32); block 256 = 4 waves; tile 128co x (2 rows x 64w)
// B LDS: per ci64-chunk [row4][wp72][64B], ci-16B-slots XOR-swizzled by wp.
__device__ __forceinline__ void stage_chunk(const int8_t* __restrict__ g0,
                                            int8_t* lbuf, int chunk, int tid) {
#pragma unroll
    for (int j = 0; j < 5; ++j) {
        int p = tid + j * 256;                      // 0..1151
        if (j < 4 || tid < 128) {
            int row = p / 288, rem = p - row * 288;
            int wp = rem >> 2, s = rem & 3;
            int g = (s - wp) & 3;
            gld16(g0 + (size_t)row * TPW * CI + wp * 256 + chunk * 64 + g * 16,
                  lbuf + p * 16);
        }
    }
}

__launch_bounds__(256, 2)
__global__ void conv_kernel(const int8_t* __restrict__ wT,
                            const int8_t* __restrict__ tp,
                            const float* __restrict__ bias,
                            const float* __restrict__ qscale,
                            float* __restrict__ out) {
    const int co_t = blockIdx.x;
    const int h0   = blockIdx.y * 2;
    const int n    = blockIdx.z;
    const int tid  = threadIdx.x;
    const int lane = tid & 63, wid = tid >> 6;
    const int l15 = lane & 15, qd = lane >> 4;
    const int m_off = (wid & 1) * 64;
    const int rowsel = wid >> 1;

    __shared__ int8_t Bsh[2 * 4 * TPW * 64];        // 36864 B, double-buffered

    i32x4 acc[4][4];
#pragma unroll
    for (int i = 0; i < 4; ++i)
#pragma unroll
        for (int j = 0; j < 4; ++j) acc[i][j] = (i32x4){0, 0, 0, 0};

    const int8_t* g0 = tp + ((size_t)n * TPH + h0) * TPW * CI;

    stage_chunk(g0, Bsh, 0, tid);
    for (int c = 0; c < 4; ++c) {
        __syncthreads();                            // stage(c) complete; compute(c-1) done
        if (c < 3) stage_chunk(g0, Bsh + ((c + 1) & 1) * 18432, c + 1, tid);
        const int8_t* lb = Bsh + (c & 1) * 18432;
#pragma unroll
        for (int kh = 0; kh < 3; ++kh) {
            const int brow = (rowsel + kh) * TPW;
#pragma unroll
            for (int kw = 0; kw < 3; ++kw) {
                const int tap = kh * 3 + kw;
                const i32x4* ap = (const i32x4*)(wT +
                    ((size_t)(tap * 4 + c) * 256 + co_t * 128 + m_off) * 64);
                i32x4 a[4], b[4];
#pragma unroll
                for (int i = 0; i < 4; ++i)
                    a[i] = ap[(i * 16 + l15) * 4 + qd];
#pragma unroll
                for (int j = 0; j < 4; ++j) {
                    int wp = j * 16 + l15 + kw;
                    int slot = (qd + wp) & 3;
                    b[j] = *(const i32x4*)&lb[(brow + wp) * 64 + slot * 16];
                }
#pragma unroll
                for (int i = 0; i < 4; ++i)
#pragma unroll
                    for (int j = 0; j < 4; ++j)
                        acc[i][j] = __builtin_amdgcn_mfma_i32_16x16x64_i8(
                            a[i], b[j], acc[i][j], 0, 0, 0);
            }
        }
    }

    // epilogue: dequant + bias + relu, fp32 NCHW
    const int h_out = h0 + rowsel;
#pragma unroll
    for (int i = 0; i < 4; ++i) {
        const int co = co_t * 128 + m_off + i * 16 + qd * 4;
        const float4 bv = *(const float4*)&bias[co];
        const float4 qv = *(const float4*)&qscale[co];
        const float bb[4] = {bv.x, bv.y, bv.z, bv.w};
        const float qq[4] = {qv.x, qv.y, qv.z, qv.w};
#pragma unroll
        for (int j = 0; j < 4; ++j) {
            const int w = j * 16 + l15;
            if (w < 56) {
                const size_t ob = (((size_t)n * CO + co) * HH + h_out) * WW + w;
#pragma unroll
                for (int r = 0; r < 4; ++r) {
                    float v = (float)acc[i][j][r] * qq[r] + bb[r];
                    out[ob + (size_t)r * (HH * WW)] = v > 0.f ? v : 0.f;
                }
            }
        }
    }
}

// ================= launch =================
extern "C" void kernel_launch(void* const* d_in, const int* in_sizes, int n_in,
                              void* d_out, int out_size, void* d_ws, size_t ws_size,
                              hipStream_t stream) {
    const float* x      = (const float*)d_in[0];
    const float* gamma  = (const float*)d_in[1];
    const float* beta   = (const float*)d_in[2];
    const float* weight = (const float*)d_in[3];
    const float* bias   = (const float*)d_in[4];
    float* out = (float*)d_out;

    // workspace layout (16B aligned)
    double* part    = (double*)d_ws;                            // 8*256*2*8 = 32768 B
    double* stats   = (double*)((char*)d_ws + 32768);           // 4096 B
    float*  qscale  = (float*) ((char*)d_ws + 36864);           // 1024 B
    int8_t* wT      = (int8_t*)((char*)d_ws + 65536);           // 589824 B
    int8_t* tp      = (int8_t*)((char*)d_ws + 1048576);         // 34209792 B

    wtrans_kernel<<<256, 256, 0, stream>>>(weight, wT, qscale);
    halo_kernel<<<64, 256, 0, stream>>>(tp);
    stats_part<<<dim3(256, 8), 256, 0, stream>>>(x, part);
    stats_final<<<1, 256, 0, stream>>>(part, gamma, beta, stats);
    ternarize_kernel<<<dim3(HH, NN), 256, 0, stream>>>(x, stats, tp);
    conv_kernel<<<dim3(2, 28, NN), 256, 0, stream>>>(wT, tp, bias, qscale, out);
}